// Round 5
// baseline (255.109 us; speedup 1.0000x reference)
//
#include <hip/hip_runtime.h>

#define N_NODES 100000
#define N_EDGES 1600000
#define D 64
#define NPB 128                                   // nodes per bucket
#define NBUCK ((N_NODES + NPB - 1) / NPB)         // 782
#define CHUNK 8192                                // edges per partition block
#define NCHUNK ((N_EDGES + CHUNK - 1) / CHUNK)    // 196

__device__ __forceinline__ unsigned short f2bf(float f) {
    unsigned bits = __float_as_uint(f);
    bits += 0x7FFF + ((bits >> 16) & 1);          // RNE
    return (unsigned short)(bits >> 16);
}
__device__ __forceinline__ float bf2f(unsigned short u) {
    return __uint_as_float((unsigned)u << 16);
}

// ---------------------------------------------------------------- x -> bf16 staging
__global__ __launch_bounds__(256) void stage_bf16(const float* __restrict__ x,
                                                  unsigned short* __restrict__ xb, int n8) {
    int t = blockIdx.x * 256 + threadIdx.x;
    if (t >= n8) return;
    const float4* xf = (const float4*)x;
    float4 a = xf[2 * t], b = xf[2 * t + 1];
    unsigned short u[8];
    u[0] = f2bf(a.x); u[1] = f2bf(a.y); u[2] = f2bf(a.z); u[3] = f2bf(a.w);
    u[4] = f2bf(b.x); u[5] = f2bf(b.y); u[6] = f2bf(b.z); u[7] = f2bf(b.w);
    *reinterpret_cast<uint4*>(xb + (size_t)t * 8) = *reinterpret_cast<const uint4*>(u);
}

// ---------------------------------------------------------------- bucket histogram (LDS-staged)
__global__ __launch_bounds__(256) void hist_kernel(const int* __restrict__ col,
                                                   int* __restrict__ bucketTotals) {
    __shared__ int h[NBUCK];
    for (int k = threadIdx.x; k < NBUCK; k += 256) h[k] = 0;
    __syncthreads();
    int base = blockIdx.x * CHUNK;
    #pragma unroll
    for (int it = 0; it < CHUNK / 256; ++it) {
        int e = base + it * 256 + threadIdx.x;
        if (e < N_EDGES) atomicAdd(&h[col[e] >> 7], 1);
    }
    __syncthreads();
    for (int k = threadIdx.x; k < NBUCK; k += 256)
        if (h[k]) atomicAdd(&bucketTotals[k], h[k]);
}

// ---------------------------------------------------------------- exclusive scan of 782 totals
__global__ __launch_bounds__(1024) void scan_kernel(const int* __restrict__ totals,
                                                    int* __restrict__ base_,
                                                    int* __restrict__ cursor) {
    int tid = threadIdx.x;
    int v = (tid < NBUCK) ? totals[tid] : 0;
    int lane = tid & 63, wave = tid >> 6;
    int s = v;
    #pragma unroll
    for (int o = 1; o < 64; o <<= 1) {
        int t = __shfl_up(s, o, 64);
        if (lane >= o) s += t;
    }
    __shared__ int ws[16];
    if (lane == 63) ws[wave] = s;
    __syncthreads();
    if (wave == 0 && lane < 16) {
        int w = ws[lane];
        #pragma unroll
        for (int o = 1; o < 16; o <<= 1) {
            int t = __shfl_up(w, o, 64);
            if (lane >= o) w += t;
        }
        ws[lane] = w;
    }
    __syncthreads();
    int excl = s - v + (wave ? ws[wave - 1] : 0);
    if (tid < NBUCK) { base_[tid] = excl; cursor[tid] = excl; }
}

// ---------------------------------------------------------------- partition into bucketed runs
__global__ __launch_bounds__(256) void partition_kernel(const int* __restrict__ row,
                                                        const int* __restrict__ col,
                                                        int* __restrict__ cursor,
                                                        int* __restrict__ edges) {
    __shared__ int cnt[NBUCK];
    __shared__ int runStart[NBUCK];
    __shared__ int rank[NBUCK];
    for (int k = threadIdx.x; k < NBUCK; k += 256) { cnt[k] = 0; rank[k] = 0; }
    __syncthreads();
    int base = blockIdx.x * CHUNK;
    #pragma unroll
    for (int it = 0; it < CHUNK / 256; ++it) {
        int e = base + it * 256 + threadIdx.x;
        if (e < N_EDGES) atomicAdd(&cnt[col[e] >> 7], 1);
    }
    __syncthreads();
    for (int k = threadIdx.x; k < NBUCK; k += 256) {
        int c = cnt[k];
        runStart[k] = c ? atomicAdd(&cursor[k], c) : 0;
    }
    __syncthreads();
    #pragma unroll
    for (int it = 0; it < CHUNK / 256; ++it) {
        int e = base + it * 256 + threadIdx.x;
        if (e < N_EDGES) {
            int d = col[e];
            int b = d >> 7;
            int r = atomicAdd(&rank[b], 1);
            edges[runStart[b] + r] = ((d & (NPB - 1)) << 17) | row[e];  // src < 2^17
        }
    }
}

// ---------------------------------------------------------------- per-bucket counting sort -> per-node CSR
__global__ __launch_bounds__(256) void sort_kernel(const int* __restrict__ edges,
                                                   const int* __restrict__ base_,
                                                   const int* __restrict__ totals,
                                                   int* __restrict__ edge_src,
                                                   int* __restrict__ off,
                                                   int* __restrict__ deg) {
    __shared__ int cnt[NPB];
    __shared__ int offL[NPB];
    __shared__ int cur[NPB];
    int tid = threadIdx.x;
    int b = blockIdx.x;
    int base = base_[b];
    int tot = totals[b];

    if (tid < NPB) cnt[tid] = 0;
    __syncthreads();
    for (int i = base + tid; i < base + tot; i += 256)
        atomicAdd(&cnt[edges[i] >> 17], 1);
    __syncthreads();

    if (tid < 64) {
        int v0 = cnt[2 * tid], v1 = cnt[2 * tid + 1];
        int s = v0 + v1;
        #pragma unroll
        for (int o = 1; o < 64; o <<= 1) {
            int t = __shfl_up(s, o, 64);
            if (tid >= o) s += t;
        }
        offL[2 * tid]     = s - v1 - v0;
        offL[2 * tid + 1] = s - v1;
        cur[2 * tid]      = s - v1 - v0;
        cur[2 * tid + 1]  = s - v1;
    }
    __syncthreads();

    for (int i = base + tid; i < base + tot; i += 256) {
        int p = edges[i];
        int l = p >> 17;
        int r = atomicAdd(&cur[l], 1);
        edge_src[base + r] = p & 0x1FFFF;
    }

    if (tid < NPB) {
        int gn = b * NPB + tid;
        if (gn < N_NODES) {
            off[gn] = base + offL[tid];
            deg[gn] = cnt[tid];
        }
    }
}

// ---------------------------------------------------------------- gather aggregation (bf16 rows)
__global__ __launch_bounds__(256) void agg_kernel(const unsigned short* __restrict__ xb,
                                                  const int* __restrict__ edge_src,
                                                  const int* __restrict__ off,
                                                  const int* __restrict__ deg,
                                                  const float* __restrict__ adj_norm,
                                                  unsigned short* __restrict__ aggb) {
    int w = (blockIdx.x * 256 + threadIdx.x) >> 6;    // node id
    int lane = threadIdx.x & 63;
    if (w >= N_NODES) return;
    int s = off[w];
    int end = s + deg[w];
    float acc = 0.f;
    int i = s;
    for (; i + 4 <= end; i += 4) {
        int s0 = edge_src[i + 0], s1 = edge_src[i + 1];
        int s2 = edge_src[i + 2], s3 = edge_src[i + 3];
        float v0 = bf2f(xb[(size_t)s0 * D + lane]);
        float v1 = bf2f(xb[(size_t)s1 * D + lane]);
        float v2 = bf2f(xb[(size_t)s2 * D + lane]);
        float v3 = bf2f(xb[(size_t)s3 * D + lane]);
        acc += v0 + v1 + v2 + v3;
    }
    for (; i < end; ++i) acc += bf2f(xb[(size_t)edge_src[i] * D + lane]);
    aggb[(size_t)w * D + lane] = f2bf(acc / adj_norm[w]);
}

// ---------------------------------------------------------------- fused dual GEMM + bias + relu
// bf16 input tiles (x_bf16 / agg_bf16) -> fp32 LDS; fp32 weights & compute.
#define STRIDE 68

__global__ __launch_bounds__(256) void fused_out_kernel(
    const unsigned short* __restrict__ xb, const unsigned short* __restrict__ aggb,
    const float* __restrict__ root_W, const float* __restrict__ root_b,
    const float* __restrict__ rel_W, float* __restrict__ out)
{
    __shared__ float in_sh[64 * STRIDE];
    __shared__ float w_sh[64 * STRIDE];

    const int tid = threadIdx.x;
    const int n0 = blockIdx.x * 64;
    const int jq = tid & 15;
    const int nq = tid >> 4;

    float acc[4][4] = {};

    for (int phase = 0; phase < 2; ++phase) {
        const float* __restrict__ W = phase ? root_W : rel_W;
        const unsigned short* __restrict__ In = phase ? xb : aggb;

        if (phase) __syncthreads();

        #pragma unroll
        for (int r = 0; r < 4; ++r) {
            int f = r * 256 + tid;
            int j = f >> 4;
            int dq = (f & 15) << 2;
            float4 wv = *reinterpret_cast<const float4*>(W + j * 64 + dq);
            *reinterpret_cast<float4*>(&w_sh[j * STRIDE + dq]) = wv;
        }
        #pragma unroll
        for (int r = 0; r < 4; ++r) {
            int f = r * 256 + tid;
            int n = f >> 4;
            int dq = (f & 15) << 2;
            int gn = n0 + n;
            float4 v = make_float4(0.f, 0.f, 0.f, 0.f);
            if (gn < N_NODES) {
                ushort4 uv = *reinterpret_cast<const ushort4*>(In + (size_t)gn * D + dq);
                v.x = bf2f(uv.x); v.y = bf2f(uv.y); v.z = bf2f(uv.z); v.w = bf2f(uv.w);
            }
            *reinterpret_cast<float4*>(&in_sh[n * STRIDE + dq]) = v;
        }
        __syncthreads();

        for (int d = 0; d < 64; d += 4) {
            float4 a[4], w[4];
            #pragma unroll
            for (int i = 0; i < 4; ++i)
                a[i] = *reinterpret_cast<const float4*>(&in_sh[(nq + 16 * i) * STRIDE + d]);
            #pragma unroll
            for (int k = 0; k < 4; ++k)
                w[k] = *reinterpret_cast<const float4*>(&w_sh[(jq + 16 * k) * STRIDE + d]);
            #pragma unroll
            for (int i = 0; i < 4; ++i)
                #pragma unroll
                for (int k = 0; k < 4; ++k)
                    acc[i][k] += a[i].x * w[k].x + a[i].y * w[k].y
                               + a[i].z * w[k].z + a[i].w * w[k].w;
        }
    }

    #pragma unroll
    for (int i = 0; i < 4; ++i) {
        int gn = n0 + nq + 16 * i;
        if (gn >= N_NODES) continue;
        #pragma unroll
        for (int k = 0; k < 4; ++k) {
            int j = jq + 16 * k;
            float v = acc[i][k] + root_b[j];
            out[(size_t)gn * D + j] = fmaxf(v, 0.0f);
        }
    }
}

// ---------------------------------------------------------------- launch
extern "C" void kernel_launch(void* const* d_in, const int* in_sizes, int n_in,
                              void* d_out, int out_size, void* d_ws, size_t ws_size,
                              hipStream_t stream)
{
    const float* x        = (const float*)d_in[0];
    const int*   row      = (const int*)d_in[1];
    const int*   col      = (const int*)d_in[2];
    const float* adj_norm = (const float*)d_in[4];
    const float* root_W   = (const float*)d_in[5];
    const float* root_b   = (const float*)d_in[6];
    const float* rel_W    = (const float*)d_in[7];
    float* out = (float*)d_out;

    char* ws = (char*)d_ws;
    unsigned short* xb   = (unsigned short*)ws;  ws += (size_t)N_NODES * D * 2;   // 12.8 MB
    unsigned short* aggb = (unsigned short*)ws;  ws += (size_t)N_NODES * D * 2;   // 12.8 MB
    int* bucketTot  = (int*)ws;     ws += (size_t)NBUCK * 4;
    int* bucketBase = (int*)ws;     ws += (size_t)NBUCK * 4;
    int* bucketCur  = (int*)ws;     ws += ((size_t)NBUCK * 4 + 15) / 16 * 16;
    int* off        = (int*)ws;     ws += (size_t)N_NODES * 4;
    int* deg        = (int*)ws;     ws += (size_t)N_NODES * 4;
    int* edges      = (int*)ws;     ws += (size_t)N_EDGES * 4;       // 6.4 MB
    int* edge_src   = (int*)ws;                                      // 6.4 MB

    hipMemsetAsync(bucketTot, 0, NBUCK * sizeof(int), stream);

    const int n8 = N_NODES * D / 8;
    stage_bf16<<<(n8 + 255) / 256, 256, 0, stream>>>(x, xb, n8);

    hist_kernel<<<NCHUNK, 256, 0, stream>>>(col, bucketTot);
    scan_kernel<<<1, 1024, 0, stream>>>(bucketTot, bucketBase, bucketCur);
    partition_kernel<<<NCHUNK, 256, 0, stream>>>(row, col, bucketCur, edges);
    sort_kernel<<<NBUCK, 256, 0, stream>>>(edges, bucketBase, bucketTot, edge_src, off, deg);

    const int aggThreads = N_NODES * 64;
    agg_kernel<<<(aggThreads + 255) / 256, 256, 0, stream>>>(xb, edge_src, off, deg, adj_norm, aggb);

    fused_out_kernel<<<(N_NODES + 63) / 64, 256, 0, stream>>>(
        xb, aggb, root_W, root_b, rel_W, out);
}

// Round 7
// 228.204 us; speedup vs baseline: 1.1179x; 1.1179x over previous
//
#include <hip/hip_runtime.h>

#define N_NODES 100000
#define N_EDGES 1600000
#define D 64
#define ROWW 128                                  // ab row width (bf16): [0,64)=agg, [64,128)=x
#define NPB 128                                   // nodes per bucket
#define NBUCK ((N_NODES + NPB - 1) / NPB)         // 782
#define CHUNK 8192                                // edges per partition block
#define NCHUNK ((N_EDGES + CHUNK - 1) / CHUNK)    // 196
#define APAD 136                                  // padded LDS row (bf16 elems)

typedef __attribute__((ext_vector_type(8))) short bf16x8;
typedef __attribute__((ext_vector_type(4))) float f32x4;

__device__ __forceinline__ unsigned short f2bf(float f) {
    unsigned bits = __float_as_uint(f);
    bits += 0x7FFF + ((bits >> 16) & 1);          // RNE
    return (unsigned short)(bits >> 16);
}

// ---------------------------------------------------------------- x -> bf16 into ab back half
__global__ __launch_bounds__(256) void stage_x(const float* __restrict__ x,
                                               unsigned short* __restrict__ ab, int n8) {
    int t = blockIdx.x * 256 + threadIdx.x;       // one thread = 8 floats
    if (t >= n8) return;
    int nrow = t >> 3, g = t & 7;
    const float4* xf = (const float4*)(x + (size_t)nrow * D + g * 8);
    float4 a = xf[0], b = xf[1];
    unsigned short u[8];
    u[0] = f2bf(a.x); u[1] = f2bf(a.y); u[2] = f2bf(a.z); u[3] = f2bf(a.w);
    u[4] = f2bf(b.x); u[5] = f2bf(b.y); u[6] = f2bf(b.z); u[7] = f2bf(b.w);
    *reinterpret_cast<uint4*>(ab + (size_t)nrow * ROWW + 64 + g * 8) =
        *reinterpret_cast<const uint4*>(u);
}

// ---------------------------------------------------------------- weights -> bf16 [64][128] = [rel_W | root_W]
__global__ __launch_bounds__(256) void stage_w(const float* __restrict__ rel_W,
                                               const float* __restrict__ root_W,
                                               unsigned short* __restrict__ Wb) {
    int t = blockIdx.x * 256 + threadIdx.x;       // 1024 threads, 8 floats each
    if (t >= 1024) return;
    int j = t >> 4, g = t & 15;
    const float* src = (g < 8) ? (rel_W + j * 64 + g * 8) : (root_W + j * 64 + (g - 8) * 8);
    unsigned short u[8];
    #pragma unroll
    for (int i = 0; i < 8; ++i) u[i] = f2bf(src[i]);
    *reinterpret_cast<uint4*>(Wb + j * ROWW + g * 8) = *reinterpret_cast<const uint4*>(u);
}

// ---------------------------------------------------------------- bucket histogram (LDS-staged)
__global__ __launch_bounds__(256) void hist_kernel(const int* __restrict__ col,
                                                   int* __restrict__ bucketTotals) {
    __shared__ int h[NBUCK];
    for (int k = threadIdx.x; k < NBUCK; k += 256) h[k] = 0;
    __syncthreads();
    int base = blockIdx.x * CHUNK;
    #pragma unroll
    for (int it = 0; it < CHUNK / 256; ++it) {
        int e = base + it * 256 + threadIdx.x;
        if (e < N_EDGES) atomicAdd(&h[col[e] >> 7], 1);
    }
    __syncthreads();
    for (int k = threadIdx.x; k < NBUCK; k += 256)
        if (h[k]) atomicAdd(&bucketTotals[k], h[k]);
}

// ---------------------------------------------------------------- exclusive scan of 782 totals
__global__ __launch_bounds__(1024) void scan_kernel(const int* __restrict__ totals,
                                                    int* __restrict__ base_,
                                                    int* __restrict__ cursor) {
    int tid = threadIdx.x;
    int v = (tid < NBUCK) ? totals[tid] : 0;
    int lane = tid & 63, wave = tid >> 6;
    int s = v;
    #pragma unroll
    for (int o = 1; o < 64; o <<= 1) {
        int t = __shfl_up(s, o, 64);
        if (lane >= o) s += t;
    }
    __shared__ int ws[16];
    if (lane == 63) ws[wave] = s;
    __syncthreads();
    if (wave == 0 && lane < 16) {
        int w = ws[lane];
        #pragma unroll
        for (int o = 1; o < 16; o <<= 1) {
            int t = __shfl_up(w, o, 64);
            if (lane >= o) w += t;
        }
        ws[lane] = w;
    }
    __syncthreads();
    int excl = s - v + (wave ? ws[wave - 1] : 0);
    if (tid < NBUCK) { base_[tid] = excl; cursor[tid] = excl; }
}

// ---------------------------------------------------------------- partition into bucketed runs
__global__ __launch_bounds__(256) void partition_kernel(const int* __restrict__ row,
                                                        const int* __restrict__ col,
                                                        int* __restrict__ cursor,
                                                        int* __restrict__ edges) {
    __shared__ int cnt[NBUCK];
    __shared__ int runStart[NBUCK];
    __shared__ int rank[NBUCK];
    for (int k = threadIdx.x; k < NBUCK; k += 256) { cnt[k] = 0; rank[k] = 0; }
    __syncthreads();
    int base = blockIdx.x * CHUNK;
    #pragma unroll
    for (int it = 0; it < CHUNK / 256; ++it) {
        int e = base + it * 256 + threadIdx.x;
        if (e < N_EDGES) atomicAdd(&cnt[col[e] >> 7], 1);
    }
    __syncthreads();
    for (int k = threadIdx.x; k < NBUCK; k += 256) {
        int c = cnt[k];
        runStart[k] = c ? atomicAdd(&cursor[k], c) : 0;
    }
    __syncthreads();
    #pragma unroll
    for (int it = 0; it < CHUNK / 256; ++it) {
        int e = base + it * 256 + threadIdx.x;
        if (e < N_EDGES) {
            int d = col[e];
            int b = d >> 7;
            int r = atomicAdd(&rank[b], 1);
            edges[runStart[b] + r] = ((d & (NPB - 1)) << 17) | row[e];  // src < 2^17
        }
    }
}

// ---------------------------------------------------------------- per-bucket counting sort -> per-node CSR
__global__ __launch_bounds__(256) void sort_kernel(const int* __restrict__ edges,
                                                   const int* __restrict__ base_,
                                                   const int* __restrict__ totals,
                                                   int* __restrict__ edge_src,
                                                   int* __restrict__ off,
                                                   int* __restrict__ deg) {
    __shared__ int cnt[NPB];
    __shared__ int offL[NPB];
    __shared__ int cur[NPB];
    int tid = threadIdx.x;
    int b = blockIdx.x;
    int base = base_[b];
    int tot = totals[b];

    if (tid < NPB) cnt[tid] = 0;
    __syncthreads();
    for (int i = base + tid; i < base + tot; i += 256)
        atomicAdd(&cnt[edges[i] >> 17], 1);
    __syncthreads();

    if (tid < 64) {
        int v0 = cnt[2 * tid], v1 = cnt[2 * tid + 1];
        int s = v0 + v1;
        #pragma unroll
        for (int o = 1; o < 64; o <<= 1) {
            int t = __shfl_up(s, o, 64);
            if (tid >= o) s += t;
        }
        offL[2 * tid]     = s - v1 - v0;
        offL[2 * tid + 1] = s - v1;
        cur[2 * tid]      = s - v1 - v0;
        cur[2 * tid + 1]  = s - v1;
    }
    __syncthreads();

    for (int i = base + tid; i < base + tot; i += 256) {
        int p = edges[i];
        int l = p >> 17;
        int r = atomicAdd(&cur[l], 1);
        edge_src[base + r] = p & 0x1FFFF;
    }

    if (tid < NPB) {
        int gn = b * NPB + tid;
        if (gn < N_NODES) {
            off[gn] = base + offL[tid];
            deg[gn] = cnt[tid];
        }
    }
}

// ---------------------------------------------------------------- gather aggregation: 2 edges/wave
// lanes 0-31 = even-offset edges, 32-63 = odd; lane loads uint (2 bf16 feats).
__global__ __launch_bounds__(256) void agg_kernel(unsigned short* __restrict__ ab,
                                                  const int* __restrict__ edge_src,
                                                  const int* __restrict__ off,
                                                  const int* __restrict__ deg,
                                                  const float* __restrict__ adj_norm) {
    int w = (blockIdx.x * 256 + threadIdx.x) >> 6;    // node id
    if (w >= N_NODES) return;
    int lane = threadIdx.x & 63;
    int half = lane >> 5, sub = lane & 31;
    int s = off[w], end = s + deg[w];
    float ax = 0.f, ay = 0.f;

    int i = s + half;
    for (; i + 2 < end; i += 4) {                     // 4 edges in flight per wave
        int s0 = edge_src[i], s1 = edge_src[i + 2];
        unsigned u0 = *reinterpret_cast<const unsigned*>(ab + (size_t)s0 * ROWW + 64 + sub * 2);
        unsigned u1 = *reinterpret_cast<const unsigned*>(ab + (size_t)s1 * ROWW + 64 + sub * 2);
        ax += __uint_as_float(u0 << 16) + __uint_as_float(u1 << 16);
        ay += __uint_as_float(u0 & 0xffff0000u) + __uint_as_float(u1 & 0xffff0000u);
    }
    if (i < end) {
        int s0 = edge_src[i];
        unsigned u0 = *reinterpret_cast<const unsigned*>(ab + (size_t)s0 * ROWW + 64 + sub * 2);
        ax += __uint_as_float(u0 << 16);
        ay += __uint_as_float(u0 & 0xffff0000u);
    }
    ax += __shfl_xor(ax, 32, 64);
    ay += __shfl_xor(ay, 32, 64);
    if (half == 0) {
        float inv = 1.0f / adj_norm[w];
        unsigned lo = f2bf(ax * inv), hi = f2bf(ay * inv);
        *reinterpret_cast<unsigned*>(ab + (size_t)w * ROWW + sub * 2) = lo | (hi << 16);
    }
}

// ---------------------------------------------------------------- fused MFMA GEMM + bias + relu
// out[n][j] = relu( ab[n][0:128] . Wb[j][0:128] + root_b[j] ), bf16 MFMA, fp32 acc.
__global__ __launch_bounds__(256) void fused_out_kernel(
    const unsigned short* __restrict__ ab, const unsigned short* __restrict__ Wb,
    const float* __restrict__ root_b, float* __restrict__ out)
{
    __shared__ unsigned short a_sh[64 * APAD];
    __shared__ unsigned short b_sh[64 * APAD];
    const int tid = threadIdx.x;
    const int n0 = blockIdx.x * 64;

    // stage A tile (64 nodes x 128 bf16): thread t copies 64 B (4 x uint4)
    {
        int r = tid >> 2, seg = tid & 3;              // seg*32 shorts = 64 B slice
        int gn = n0 + r;
        uint4 v0 = {0, 0, 0, 0}, v1 = {0, 0, 0, 0}, v2 = {0, 0, 0, 0}, v3 = {0, 0, 0, 0};
        if (gn < N_NODES) {
            const uint4* src = (const uint4*)(ab + (size_t)gn * ROWW + seg * 32);
            v0 = src[0]; v1 = src[1]; v2 = src[2]; v3 = src[3];
        }
        uint4* dst = (uint4*)(a_sh + r * APAD + seg * 32);
        dst[0] = v0; dst[1] = v1; dst[2] = v2; dst[3] = v3;
    }
    // stage B tile (64 outs x 128 bf16 weights): 64 B per thread
    {
        int r = tid >> 2, seg = tid & 3;
        const uint4* src = (const uint4*)(Wb + r * ROWW + seg * 32);
        uint4* dst = (uint4*)(b_sh + r * APAD + seg * 32);
        dst[0] = src[0]; dst[1] = src[1]; dst[2] = src[2]; dst[3] = src[3];
    }
    __syncthreads();

    const int wv = tid >> 6, lane = tid & 63;
    const int quad = lane >> 4, l15 = lane & 15;

    bf16x8 afrag[4];
    const int abase = (wv * 16 + l15) * APAD + quad * 8;
    #pragma unroll
    for (int kk = 0; kk < 4; ++kk)
        afrag[kk] = *reinterpret_cast<const bf16x8*>(a_sh + abase + kk * 32);

    f32x4 acc[4] = {};
    #pragma unroll
    for (int t = 0; t < 4; ++t) {
        const int bbase = (t * 16 + l15) * APAD + quad * 8;
        #pragma unroll
        for (int kk = 0; kk < 4; ++kk) {
            bf16x8 bfrag = *reinterpret_cast<const bf16x8*>(b_sh + bbase + kk * 32);
            acc[t] = __builtin_amdgcn_mfma_f32_16x16x32_bf16(afrag[kk], bfrag, acc[t], 0, 0, 0);
        }
    }

    // epilogue: C/D layout col=lane&15, row=quad*4+reg
    #pragma unroll
    for (int t = 0; t < 4; ++t) {
        int j = t * 16 + l15;
        float bias = root_b[j];
        #pragma unroll
        for (int r = 0; r < 4; ++r) {
            int node = n0 + wv * 16 + quad * 4 + r;
            if (node < N_NODES) {
                float v = acc[t][r] + bias;
                out[(size_t)node * D + j] = fmaxf(v, 0.0f);
            }
        }
    }
}

// ---------------------------------------------------------------- launch
extern "C" void kernel_launch(void* const* d_in, const int* in_sizes, int n_in,
                              void* d_out, int out_size, void* d_ws, size_t ws_size,
                              hipStream_t stream)
{
    const float* x        = (const float*)d_in[0];
    const int*   row      = (const int*)d_in[1];
    const int*   col      = (const int*)d_in[2];
    const float* adj_norm = (const float*)d_in[4];
    const float* root_W   = (const float*)d_in[5];
    const float* root_b   = (const float*)d_in[6];
    const float* rel_W    = (const float*)d_in[7];
    float* out = (float*)d_out;

    char* ws = (char*)d_ws;
    unsigned short* ab = (unsigned short*)ws;  ws += (size_t)N_NODES * ROWW * 2;  // 25.6 MB
    unsigned short* Wb = (unsigned short*)ws;  ws += 64 * ROWW * 2;               // 16 KB
    int* bucketTot  = (int*)ws;  ws += ((size_t)NBUCK * 4 + 15) / 16 * 16;
    int* bucketBase = (int*)ws;  ws += ((size_t)NBUCK * 4 + 15) / 16 * 16;
    int* bucketCur  = (int*)ws;  ws += ((size_t)NBUCK * 4 + 15) / 16 * 16;
    int* off        = (int*)ws;  ws += (size_t)N_NODES * 4;
    int* deg        = (int*)ws;  ws += (size_t)N_NODES * 4;
    int* edges      = (int*)ws;  ws += (size_t)N_EDGES * 4;                       // 6.4 MB
    int* edge_src   = (int*)ws;                                                   // 6.4 MB

    hipMemsetAsync(bucketTot, 0, NBUCK * sizeof(int), stream);

    const int n8 = N_NODES * D / 8;
    stage_x<<<(n8 + 255) / 256, 256, 0, stream>>>(x, ab, n8);
    stage_w<<<4, 256, 0, stream>>>(rel_W, root_W, Wb);

    hist_kernel<<<NCHUNK, 256, 0, stream>>>(col, bucketTot);
    scan_kernel<<<1, 1024, 0, stream>>>(bucketTot, bucketBase, bucketCur);
    partition_kernel<<<NCHUNK, 256, 0, stream>>>(row, col, bucketCur, edges);
    sort_kernel<<<NBUCK, 256, 0, stream>>>(edges, bucketBase, bucketTot, edge_src, off, deg);

    const int aggThreads = N_NODES * 64;
    agg_kernel<<<(aggThreads + 255) / 256, 256, 0, stream>>>(ab, edge_src, off, deg, adj_norm);

    fused_out_kernel<<<(N_NODES + 63) / 64, 256, 0, stream>>>(ab, Wb, root_b, out);
}

// Round 8
// 193.895 us; speedup vs baseline: 1.3157x; 1.1769x over previous
//
#include <hip/hip_runtime.h>

#define N_NODES 100000
#define N_EDGES 1600000
#define D 64
#define ROWW 128                                  // ab row width (bf16): [0,64)=agg, [64,128)=x
#define NPB 128                                   // nodes per bucket
#define NBUCK ((N_NODES + NPB - 1) / NPB)         // 782
#define CHUNK 8192                                // edges per partition block
#define NCHUNK ((N_EDGES + CHUNK - 1) / CHUNK)    // 196
#define APAD 136                                  // padded LDS row (bf16 elems)

typedef __attribute__((ext_vector_type(8))) short bf16x8;
typedef __attribute__((ext_vector_type(4))) float f32x4;

__device__ __forceinline__ unsigned short f2bf(float f) {
    unsigned bits = __float_as_uint(f);
    bits += 0x7FFF + ((bits >> 16) & 1);          // RNE
    return (unsigned short)(bits >> 16);
}

// ---------------------------------------------------------------- x -> bf16 into ab back half
__global__ __launch_bounds__(256) void stage_x(const float* __restrict__ x,
                                               unsigned short* __restrict__ ab, int n8) {
    int t = blockIdx.x * 256 + threadIdx.x;       // one thread = 8 floats
    if (t >= n8) return;
    int nrow = t >> 3, g = t & 7;
    const float4* xf = (const float4*)(x + (size_t)nrow * D + g * 8);
    float4 a = xf[0], b = xf[1];
    unsigned short u[8];
    u[0] = f2bf(a.x); u[1] = f2bf(a.y); u[2] = f2bf(a.z); u[3] = f2bf(a.w);
    u[4] = f2bf(b.x); u[5] = f2bf(b.y); u[6] = f2bf(b.z); u[7] = f2bf(b.w);
    *reinterpret_cast<uint4*>(ab + (size_t)nrow * ROWW + 64 + g * 8) =
        *reinterpret_cast<const uint4*>(u);
}

// ---------------------------------------------------------------- weights -> bf16 [64][128] = [rel_W | root_W]
__global__ __launch_bounds__(256) void stage_w(const float* __restrict__ rel_W,
                                               const float* __restrict__ root_W,
                                               unsigned short* __restrict__ Wb) {
    int t = blockIdx.x * 256 + threadIdx.x;       // 1024 threads, 8 floats each
    if (t >= 1024) return;
    int j = t >> 4, g = t & 15;
    const float* src = (g < 8) ? (rel_W + j * 64 + g * 8) : (root_W + j * 64 + (g - 8) * 8);
    unsigned short u[8];
    #pragma unroll
    for (int i = 0; i < 8; ++i) u[i] = f2bf(src[i]);
    *reinterpret_cast<uint4*>(Wb + j * ROWW + g * 8) = *reinterpret_cast<const uint4*>(u);
}

// ---------------------------------------------------------------- bucket histogram (LDS-staged)
__global__ __launch_bounds__(1024) void hist_kernel(const int* __restrict__ col,
                                                    int* __restrict__ bucketTotals) {
    __shared__ int h[NBUCK];
    for (int k = threadIdx.x; k < NBUCK; k += 1024) h[k] = 0;
    __syncthreads();
    int base = blockIdx.x * CHUNK;
    #pragma unroll
    for (int it = 0; it < CHUNK / 1024; ++it) {
        int e = base + it * 1024 + threadIdx.x;
        if (e < N_EDGES) atomicAdd(&h[col[e] >> 7], 1);
    }
    __syncthreads();
    for (int k = threadIdx.x; k < NBUCK; k += 1024)
        if (h[k]) atomicAdd(&bucketTotals[k], h[k]);
}

// ---------------------------------------------------------------- exclusive scan of 782 totals
__global__ __launch_bounds__(1024) void scan_kernel(const int* __restrict__ totals,
                                                    int* __restrict__ base_,
                                                    int* __restrict__ cursor) {
    int tid = threadIdx.x;
    int v = (tid < NBUCK) ? totals[tid] : 0;
    int lane = tid & 63, wave = tid >> 6;
    int s = v;
    #pragma unroll
    for (int o = 1; o < 64; o <<= 1) {
        int t = __shfl_up(s, o, 64);
        if (lane >= o) s += t;
    }
    __shared__ int ws[16];
    if (lane == 63) ws[wave] = s;
    __syncthreads();
    if (wave == 0 && lane < 16) {
        int w = ws[lane];
        #pragma unroll
        for (int o = 1; o < 16; o <<= 1) {
            int t = __shfl_up(w, o, 64);
            if (lane >= o) w += t;
        }
        ws[lane] = w;
    }
    __syncthreads();
    int excl = s - v + (wave ? ws[wave - 1] : 0);
    if (tid < NBUCK) { base_[tid] = excl; cursor[tid] = excl; }
}

// ---------------------------------------------------------------- partition into bucketed runs
__global__ __launch_bounds__(1024) void partition_kernel(const int* __restrict__ row,
                                                         const int* __restrict__ col,
                                                         int* __restrict__ cursor,
                                                         int* __restrict__ edges) {
    __shared__ int cnt[NBUCK];
    __shared__ int runStart[NBUCK];
    __shared__ int rank[NBUCK];
    for (int k = threadIdx.x; k < NBUCK; k += 1024) { cnt[k] = 0; rank[k] = 0; }
    __syncthreads();
    int base = blockIdx.x * CHUNK;
    #pragma unroll
    for (int it = 0; it < CHUNK / 1024; ++it) {
        int e = base + it * 1024 + threadIdx.x;
        if (e < N_EDGES) atomicAdd(&cnt[col[e] >> 7], 1);
    }
    __syncthreads();
    for (int k = threadIdx.x; k < NBUCK; k += 1024) {
        int c = cnt[k];
        runStart[k] = c ? atomicAdd(&cursor[k], c) : 0;
    }
    __syncthreads();
    #pragma unroll
    for (int it = 0; it < CHUNK / 1024; ++it) {
        int e = base + it * 1024 + threadIdx.x;
        if (e < N_EDGES) {
            int d = col[e];
            int b = d >> 7;
            int r = atomicAdd(&rank[b], 1);
            edges[runStart[b] + r] = ((d & (NPB - 1)) << 17) | row[e];  // src < 2^17
        }
    }
}

// ---------------------------------------------------------------- per-bucket counting sort -> per-node CSR
__global__ __launch_bounds__(512) void sort_kernel(const int* __restrict__ edges,
                                                   const int* __restrict__ base_,
                                                   const int* __restrict__ totals,
                                                   int* __restrict__ edge_src,
                                                   int* __restrict__ off,
                                                   int* __restrict__ deg) {
    __shared__ int cnt[NPB];
    __shared__ int offL[NPB];
    __shared__ int cur[NPB];
    int tid = threadIdx.x;
    int b = blockIdx.x;
    int base = base_[b];
    int tot = totals[b];

    if (tid < NPB) cnt[tid] = 0;
    __syncthreads();
    for (int i = base + tid; i < base + tot; i += 512)
        atomicAdd(&cnt[edges[i] >> 17], 1);
    __syncthreads();

    if (tid < 64) {
        int v0 = cnt[2 * tid], v1 = cnt[2 * tid + 1];
        int s = v0 + v1;
        #pragma unroll
        for (int o = 1; o < 64; o <<= 1) {
            int t = __shfl_up(s, o, 64);
            if (tid >= o) s += t;
        }
        offL[2 * tid]     = s - v1 - v0;
        offL[2 * tid + 1] = s - v1;
        cur[2 * tid]      = s - v1 - v0;
        cur[2 * tid + 1]  = s - v1;
    }
    __syncthreads();

    for (int i = base + tid; i < base + tot; i += 512) {
        int p = edges[i];
        int l = p >> 17;
        int r = atomicAdd(&cur[l], 1);
        edge_src[base + r] = p & 0x1FFFF;
    }

    if (tid < NPB) {
        int gn = b * NPB + tid;
        if (gn < N_NODES) {
            off[gn] = base + offL[tid];
            deg[gn] = cnt[tid];
        }
    }
}

// ---------------------------------------------------------------- gather aggregation: 4 edges/instr, 16 in flight
// quarter q handles edges q, q+4, ...; lane loads uint2 (4 bf16 feats);
// indices preloaded 64-at-a-time and broadcast via shfl (off the gather chain).
__global__ __launch_bounds__(256) void agg_kernel(unsigned short* __restrict__ ab,
                                                  const int* __restrict__ edge_src,
                                                  const int* __restrict__ off,
                                                  const int* __restrict__ deg,
                                                  const float* __restrict__ adj_norm) {
    int w = (blockIdx.x * 256 + threadIdx.x) >> 6;    // node id
    if (w >= N_NODES) return;
    int lane = threadIdx.x & 63;
    int q = lane >> 4, sub = lane & 15;
    int s = off[w], dg = deg[w];
    const unsigned short* __restrict__ xh = ab + 64 + sub * 4;   // x-half feature slot

    float a0 = 0.f, a1 = 0.f, a2 = 0.f, a3 = 0.f;
    int base = 0;
    int idx = (lane < dg) ? edge_src[s + lane] : 0;

    while (true) {
        int lim = dg - base; if (lim > 64) lim = 64;
        int eb = 0;
        for (; eb + 16 <= lim; eb += 16) {            // 16 edges, 4 gather instrs in flight
            int i0 = __shfl(idx, eb + q);
            int i1 = __shfl(idx, eb + q + 4);
            int i2 = __shfl(idx, eb + q + 8);
            int i3 = __shfl(idx, eb + q + 12);
            uint2 u0 = *reinterpret_cast<const uint2*>(xh + (size_t)i0 * ROWW);
            uint2 u1 = *reinterpret_cast<const uint2*>(xh + (size_t)i1 * ROWW);
            uint2 u2 = *reinterpret_cast<const uint2*>(xh + (size_t)i2 * ROWW);
            uint2 u3 = *reinterpret_cast<const uint2*>(xh + (size_t)i3 * ROWW);
            a0 += __uint_as_float(u0.x << 16) + __uint_as_float(u1.x << 16)
                + __uint_as_float(u2.x << 16) + __uint_as_float(u3.x << 16);
            a1 += __uint_as_float(u0.x & 0xffff0000u) + __uint_as_float(u1.x & 0xffff0000u)
                + __uint_as_float(u2.x & 0xffff0000u) + __uint_as_float(u3.x & 0xffff0000u);
            a2 += __uint_as_float(u0.y << 16) + __uint_as_float(u1.y << 16)
                + __uint_as_float(u2.y << 16) + __uint_as_float(u3.y << 16);
            a3 += __uint_as_float(u0.y & 0xffff0000u) + __uint_as_float(u1.y & 0xffff0000u)
                + __uint_as_float(u2.y & 0xffff0000u) + __uint_as_float(u3.y & 0xffff0000u);
        }
        if (eb < lim) {                               // tail: ceil(rem/4) steps, predicated
            int nst = (lim - eb + 3) >> 2;
            for (int t = 0; t < nst; ++t) {
                int e = eb + q + t * 4;
                int ii = __shfl(idx, e & 63);
                uint2 u = *reinterpret_cast<const uint2*>(xh + (size_t)ii * ROWW);
                if (e < lim) {
                    a0 += __uint_as_float(u.x << 16);
                    a1 += __uint_as_float(u.x & 0xffff0000u);
                    a2 += __uint_as_float(u.y << 16);
                    a3 += __uint_as_float(u.y & 0xffff0000u);
                }
            }
        }
        base += 64;
        if (base >= dg) break;
        idx = (base + lane < dg) ? edge_src[s + base + lane] : 0;
    }

    a0 += __shfl_xor(a0, 16, 64); a0 += __shfl_xor(a0, 32, 64);
    a1 += __shfl_xor(a1, 16, 64); a1 += __shfl_xor(a1, 32, 64);
    a2 += __shfl_xor(a2, 16, 64); a2 += __shfl_xor(a2, 32, 64);
    a3 += __shfl_xor(a3, 16, 64); a3 += __shfl_xor(a3, 32, 64);

    if (q == 0) {
        float inv = 1.0f / adj_norm[w];
        uint2 p;
        p.x = (unsigned)f2bf(a0 * inv) | ((unsigned)f2bf(a1 * inv) << 16);
        p.y = (unsigned)f2bf(a2 * inv) | ((unsigned)f2bf(a3 * inv) << 16);
        *reinterpret_cast<uint2*>(ab + (size_t)w * ROWW + sub * 4) = p;
    }
}

// ---------------------------------------------------------------- fused MFMA GEMM + bias + relu
__global__ __launch_bounds__(256) void fused_out_kernel(
    const unsigned short* __restrict__ ab, const unsigned short* __restrict__ Wb,
    const float* __restrict__ root_b, float* __restrict__ out)
{
    __shared__ unsigned short a_sh[64 * APAD];
    __shared__ unsigned short b_sh[64 * APAD];
    const int tid = threadIdx.x;
    const int n0 = blockIdx.x * 64;

    {
        int r = tid >> 2, seg = tid & 3;              // 64 B slice per thread
        int gn = n0 + r;
        uint4 v0 = {0,0,0,0}, v1 = {0,0,0,0}, v2 = {0,0,0,0}, v3 = {0,0,0,0};
        if (gn < N_NODES) {
            const uint4* src = (const uint4*)(ab + (size_t)gn * ROWW + seg * 32);
            v0 = src[0]; v1 = src[1]; v2 = src[2]; v3 = src[3];
        }
        uint4* dst = (uint4*)(a_sh + r * APAD + seg * 32);
        dst[0] = v0; dst[1] = v1; dst[2] = v2; dst[3] = v3;
    }
    {
        int r = tid >> 2, seg = tid & 3;
        const uint4* src = (const uint4*)(Wb + r * ROWW + seg * 32);
        uint4* dst = (uint4*)(b_sh + r * APAD + seg * 32);
        dst[0] = src[0]; dst[1] = src[1]; dst[2] = src[2]; dst[3] = src[3];
    }
    __syncthreads();

    const int wv = tid >> 6, lane = tid & 63;
    const int quad = lane >> 4, l15 = lane & 15;

    bf16x8 afrag[4];
    const int abase = (wv * 16 + l15) * APAD + quad * 8;
    #pragma unroll
    for (int kk = 0; kk < 4; ++kk)
        afrag[kk] = *reinterpret_cast<const bf16x8*>(a_sh + abase + kk * 32);

    f32x4 acc[4] = {};
    #pragma unroll
    for (int t = 0; t < 4; ++t) {
        const int bbase = (t * 16 + l15) * APAD + quad * 8;
        #pragma unroll
        for (int kk = 0; kk < 4; ++kk) {
            bf16x8 bfrag = *reinterpret_cast<const bf16x8*>(b_sh + bbase + kk * 32);
            acc[t] = __builtin_amdgcn_mfma_f32_16x16x32_bf16(afrag[kk], bfrag, acc[t], 0, 0, 0);
        }
    }

    #pragma unroll
    for (int t = 0; t < 4; ++t) {
        int j = t * 16 + l15;
        float bias = root_b[j];
        #pragma unroll
        for (int r = 0; r < 4; ++r) {
            int node = n0 + wv * 16 + quad * 4 + r;
            if (node < N_NODES) {
                float v = acc[t][r] + bias;
                out[(size_t)node * D + j] = fmaxf(v, 0.0f);
            }
        }
    }
}

// ---------------------------------------------------------------- launch
extern "C" void kernel_launch(void* const* d_in, const int* in_sizes, int n_in,
                              void* d_out, int out_size, void* d_ws, size_t ws_size,
                              hipStream_t stream)
{
    const float* x        = (const float*)d_in[0];
    const int*   row      = (const int*)d_in[1];
    const int*   col      = (const int*)d_in[2];
    const float* adj_norm = (const float*)d_in[4];
    const float* root_W   = (const float*)d_in[5];
    const float* root_b   = (const float*)d_in[6];
    const float* rel_W    = (const float*)d_in[7];
    float* out = (float*)d_out;

    char* ws = (char*)d_ws;
    unsigned short* ab = (unsigned short*)ws;  ws += (size_t)N_NODES * ROWW * 2;  // 25.6 MB
    unsigned short* Wb = (unsigned short*)ws;  ws += 64 * ROWW * 2;               // 16 KB
    int* bucketTot  = (int*)ws;  ws += ((size_t)NBUCK * 4 + 15) / 16 * 16;
    int* bucketBase = (int*)ws;  ws += ((size_t)NBUCK * 4 + 15) / 16 * 16;
    int* bucketCur  = (int*)ws;  ws += ((size_t)NBUCK * 4 + 15) / 16 * 16;
    int* off        = (int*)ws;  ws += (size_t)N_NODES * 4;
    int* deg        = (int*)ws;  ws += (size_t)N_NODES * 4;
    int* edges      = (int*)ws;  ws += (size_t)N_EDGES * 4;                       // 6.4 MB
    int* edge_src   = (int*)ws;                                                   // 6.4 MB

    hipMemsetAsync(bucketTot, 0, NBUCK * sizeof(int), stream);

    const int n8 = N_NODES * D / 8;
    stage_x<<<(n8 + 255) / 256, 256, 0, stream>>>(x, ab, n8);
    stage_w<<<4, 256, 0, stream>>>(rel_W, root_W, Wb);

    hist_kernel<<<NCHUNK, 1024, 0, stream>>>(col, bucketTot);
    scan_kernel<<<1, 1024, 0, stream>>>(bucketTot, bucketBase, bucketCur);
    partition_kernel<<<NCHUNK, 1024, 0, stream>>>(row, col, bucketCur, edges);
    sort_kernel<<<NBUCK, 512, 0, stream>>>(edges, bucketBase, bucketTot, edge_src, off, deg);

    const int aggThreads = N_NODES * 64;
    agg_kernel<<<(aggThreads + 255) / 256, 256, 0, stream>>>(ab, edge_src, off, deg, adj_norm);

    fused_out_kernel<<<(N_NODES + 63) / 64, 256, 0, stream>>>(ab, Wb, root_b, out);
}